// Round 8
// baseline (622.602 us; speedup 1.0000x reference)
//
#include <hip/hip_runtime.h>
#include <math.h>

#define THREADS 256

typedef __attribute__((ext_vector_type(8))) short short8;
typedef __attribute__((ext_vector_type(4))) float f32x4;

static __device__ __forceinline__ ushort f2bf(float f) {
    uint u = __float_as_uint(f);
    uint r = (u + 0x7FFFu + ((u >> 16) & 1u)) >> 16;   // RNE
    return (ushort)r;
}
static __device__ __forceinline__ float bf2f(ushort h) {
    return __uint_as_float(((uint)h) << 16);
}
static __device__ __forceinline__ uint pack2(float a, float b) {
    return (uint)f2bf(a) | ((uint)f2bf(b) << 16);
}
// async global->LDS, 16B per lane; LDS dest = wave-uniform base + lane*16
static __device__ __forceinline__ void gload16(const ushort* g, ushort* l) {
    __builtin_amdgcn_global_load_lds(
        (const __attribute__((address_space(1))) void*)g,
        (__attribute__((address_space(3))) void*)l, 16, 0, 0);
}
// accumulate 8 bf16 (as uint4) into 8 fp32
static __device__ __forceinline__ void acc8(float* s, uint4 v) {
    s[0] += bf2f((ushort)v.x); s[1] += bf2f((ushort)(v.x >> 16));
    s[2] += bf2f((ushort)v.y); s[3] += bf2f((ushort)(v.y >> 16));
    s[4] += bf2f((ushort)v.z); s[5] += bf2f((ushort)(v.z >> 16));
    s[6] += bf2f((ushort)v.w); s[7] += bf2f((ushort)(v.w >> 16));
}

// ---------------- fused CSR-count + x->bf16 convert ----------------
__global__ void count_convert(const int* __restrict__ pdst, const int* __restrict__ ndst,
                              int* pcnt, int* ncnt,
                              ushort* __restrict__ prank, ushort* __restrict__ nrank,
                              int E, int cblk,
                              const float* __restrict__ x, ushort* __restrict__ xb, long n8) {
    if ((int)blockIdx.x < cblk) {
        int e = blockIdx.x * blockDim.x + threadIdx.x;
        if (e < E) {
            prank[e] = (ushort)atomicAdd(&pcnt[pdst[e]], 1);
            nrank[e] = (ushort)atomicAdd(&ncnt[ndst[e]], 1);
        }
    } else {
        long o = (long)(blockIdx.x - cblk) * blockDim.x + threadIdx.x;
        if (o < n8) {
            long base = o * 8;
            float4 f0 = *(const float4*)(x + base);
            float4 f1 = *(const float4*)(x + base + 4);
            uint4 u;
            u.x = pack2(f0.x, f0.y);
            u.y = pack2(f0.z, f0.w);
            u.z = pack2(f1.x, f1.y);
            u.w = pack2(f1.z, f1.w);
            *(uint4*)(xb + base) = u;
        }
    }
}

// two independent in-place exclusive scans (block 0 -> a, block 1 -> b); rp[n]=total
__global__ __launch_bounds__(1024) void scan2_kernel(int* a, int* b, int n) {
    int* rp = blockIdx.x ? b : a;
    __shared__ int sums[1024];
    int t = threadIdx.x;
    int ch = (n + 1023) >> 10;
    int beg = t * ch;
    int end = min(beg + ch, n);
    int s = 0;
    for (int i = beg; i < end; i++) s += rp[i];
    sums[t] = s;
    __syncthreads();
    for (int off = 1; off < 1024; off <<= 1) {
        int v = (t >= off) ? sums[t - off] : 0;
        __syncthreads();
        sums[t] += v;
        __syncthreads();
    }
    int run = (t > 0) ? sums[t - 1] : 0;
    for (int i = beg; i < end; i++) {
        int c = rp[i];
        rp[i] = run;
        run += c;
    }
    if (t == 1023) rp[n] = sums[1023];
}

// ---------------- fused CSR-fill + weight transpose ----------------
__global__ void fill_transpose(const int* __restrict__ psrc, const int* __restrict__ pdst,
                               const int* __restrict__ nsrc, const int* __restrict__ ndst,
                               const int* __restrict__ prow, const int* __restrict__ nrow,
                               const ushort* __restrict__ prank, const ushort* __restrict__ nrank,
                               ushort* __restrict__ pperm, ushort* __restrict__ nperm,
                               int E, int fblk,
                               const float* W1, ushort* T1, const float* W2, ushort* T2,
                               const float* W3, ushort* T3, const float* W4, ushort* T4,
                               const float* W5, ushort* T5, int D) {
    if ((int)blockIdx.x < fblk) {
        int e = blockIdx.x * blockDim.x + threadIdx.x;
        if (e < E) {
            pperm[prow[pdst[e]] + prank[e]] = (ushort)psrc[e];
            nperm[nrow[ndst[e]] + nrank[e]] = (ushort)nsrc[e];
        }
    } else {
        int o = (blockIdx.x - fblk) * blockDim.x + threadIdx.x;
        int s1 = 2 * D * D, s3 = 6 * D * D, s5 = 4 * D * D;
        const float* W; ushort* T; int K, C;
        int off = o;
        if (off < s1)              { W = W1; T = T1; K = 2 * D; C = D; }
        else if ((off -= s1) < s1) { W = W2; T = T2; K = 2 * D; C = D; }
        else if ((off -= s1) < s3) { W = W3; T = T3; K = 3 * D; C = 2 * D; }
        else if ((off -= s3) < s3) { W = W4; T = T4; K = 3 * D; C = 2 * D; }
        else if ((off -= s3) < s5) { W = W5; T = T5; K = 4 * D; C = D; }
        else return;
        int c = off / K, k = off - c * K;
        T[off] = f2bf(W[(long)k * C + c]);
    }
}

// ---------------- gathers: 1 node/wave, uint4 loads, pos/neg interleaved ----------------
// layer 1: 4 edge-groups x 16 lanes (16B/lane covers the 256B row)
__global__ __launch_bounds__(256) void gather_l1(
        const int* __restrict__ p_row, const int* __restrict__ n_row,
        const ushort* __restrict__ p_perm, const ushort* __restrict__ n_perm,
        const ushort* __restrict__ xb, ushort* __restrict__ mpn, int n) {
    int node = blockIdx.x * 4 + (threadIdx.x >> 6);
    if (node >= n) return;
    int lane = threadIdx.x & 63;
    int g = lane >> 4, l = lane & 15;
    const ushort* rb = xb + l * 8;

    float sp[8] = {0,0,0,0,0,0,0,0}, sn[8] = {0,0,0,0,0,0,0,0};

    int i = p_row[node], ep = p_row[node + 1];
    int j = n_row[node], en = n_row[node + 1];
    float invp = 1.0f / (float)max(ep - i, 1);
    float invn = 1.0f / (float)max(en - j, 1);

    // main: both signs in flight (4 uint4 outstanding per lane)
    while (i + 8 <= ep && j + 8 <= en) {
        uint4 a0 = *(const uint4*)(rb + (long)p_perm[i + g] * 128);
        uint4 a1 = *(const uint4*)(rb + (long)p_perm[i + 4 + g] * 128);
        uint4 c0 = *(const uint4*)(rb + (long)n_perm[j + g] * 128);
        uint4 c1 = *(const uint4*)(rb + (long)n_perm[j + 4 + g] * 128);
        acc8(sp, a0); acc8(sp, a1); acc8(sn, c0); acc8(sn, c1);
        i += 8; j += 8;
    }
    for (; i + 8 <= ep; i += 8) {
        uint4 a0 = *(const uint4*)(rb + (long)p_perm[i + g] * 128);
        uint4 a1 = *(const uint4*)(rb + (long)p_perm[i + 4 + g] * 128);
        acc8(sp, a0); acc8(sp, a1);
    }
    for (; i + g < ep; i += 4) {
        uint4 a0 = *(const uint4*)(rb + (long)p_perm[i + g] * 128);
        acc8(sp, a0);
    }
    for (; j + 8 <= en; j += 8) {
        uint4 c0 = *(const uint4*)(rb + (long)n_perm[j + g] * 128);
        uint4 c1 = *(const uint4*)(rb + (long)n_perm[j + 4 + g] * 128);
        acc8(sn, c0); acc8(sn, c1);
    }
    for (; j + g < en; j += 4) {
        uint4 c0 = *(const uint4*)(rb + (long)n_perm[j + g] * 128);
        acc8(sn, c0);
    }

#pragma unroll
    for (int q = 0; q < 8; q++) {
        sp[q] += __shfl_xor(sp[q], 16);
        sp[q] += __shfl_xor(sp[q], 32);
        sn[q] += __shfl_xor(sn[q], 16);
        sn[q] += __shfl_xor(sn[q], 32);
    }

    if (g == 0) {
        uint4 o;
        o.x = pack2(sp[0] * invp, sp[1] * invp);
        o.y = pack2(sp[2] * invp, sp[3] * invp);
        o.z = pack2(sp[4] * invp, sp[5] * invp);
        o.w = pack2(sp[6] * invp, sp[7] * invp);
        *(uint4*)(mpn + (long)node * 256 + l * 8) = o;
    } else if (g == 1) {
        uint4 o;
        o.x = pack2(sn[0] * invn, sn[1] * invn);
        o.y = pack2(sn[2] * invn, sn[3] * invn);
        o.z = pack2(sn[4] * invn, sn[5] * invn);
        o.w = pack2(sn[6] * invn, sn[7] * invn);
        *(uint4*)(mpn + (long)node * 256 + 128 + l * 8) = o;
    }
}

// layer 2: 2 edge-groups x 32 lanes (16B/lane covers the 512B [hb1|hn1] row)
__global__ __launch_bounds__(256) void gather_l2(
        const int* __restrict__ p_row, const int* __restrict__ n_row,
        const ushort* __restrict__ p_perm, const ushort* __restrict__ n_perm,
        const ushort* __restrict__ hbn1,
        ushort* __restrict__ pos2, ushort* __restrict__ neg2, int n) {
    int node = blockIdx.x * 4 + (threadIdx.x >> 6);
    if (node >= n) return;
    int lane = threadIdx.x & 63;
    int g = lane >> 5, l = lane & 31;
    const ushort* rb = hbn1 + l * 8;

    float sp[8] = {0,0,0,0,0,0,0,0}, sn[8] = {0,0,0,0,0,0,0,0};

    int i = p_row[node], ep = p_row[node + 1];
    int j = n_row[node], en = n_row[node + 1];
    float invp = 1.0f / (float)max(ep - i, 1);
    float invn = 1.0f / (float)max(en - j, 1);

    while (i + 4 <= ep && j + 4 <= en) {
        uint4 a0 = *(const uint4*)(rb + (long)p_perm[i + g] * 256);
        uint4 a1 = *(const uint4*)(rb + (long)p_perm[i + 2 + g] * 256);
        uint4 c0 = *(const uint4*)(rb + (long)n_perm[j + g] * 256);
        uint4 c1 = *(const uint4*)(rb + (long)n_perm[j + 2 + g] * 256);
        acc8(sp, a0); acc8(sp, a1); acc8(sn, c0); acc8(sn, c1);
        i += 4; j += 4;
    }
    for (; i + 4 <= ep; i += 4) {
        uint4 a0 = *(const uint4*)(rb + (long)p_perm[i + g] * 256);
        uint4 a1 = *(const uint4*)(rb + (long)p_perm[i + 2 + g] * 256);
        acc8(sp, a0); acc8(sp, a1);
    }
    for (; i + g < ep; i += 2) {
        uint4 a0 = *(const uint4*)(rb + (long)p_perm[i + g] * 256);
        acc8(sp, a0);
    }
    for (; j + 4 <= en; j += 4) {
        uint4 c0 = *(const uint4*)(rb + (long)n_perm[j + g] * 256);
        uint4 c1 = *(const uint4*)(rb + (long)n_perm[j + 2 + g] * 256);
        acc8(sn, c0); acc8(sn, c1);
    }
    for (; j + g < en; j += 2) {
        uint4 c0 = *(const uint4*)(rb + (long)n_perm[j + g] * 256);
        acc8(sn, c0);
    }

#pragma unroll
    for (int q = 0; q < 8; q++) {
        sp[q] += __shfl_xor(sp[q], 32);
        sn[q] += __shfl_xor(sn[q], 32);
    }

    // pos2[node] = [mean_pos(hb1) | mean_neg(hn1)]
    // neg2[node] = [mean_pos(hn1) | mean_neg(hb1)]
    bool useP = (g == 0) ? (l < 16) : (l >= 16);
    float sc = useP ? invp : invn;
    float v0 = (useP ? sp[0] : sn[0]) * sc, v1 = (useP ? sp[1] : sn[1]) * sc;
    float v2 = (useP ? sp[2] : sn[2]) * sc, v3 = (useP ? sp[3] : sn[3]) * sc;
    float v4 = (useP ? sp[4] : sn[4]) * sc, v5 = (useP ? sp[5] : sn[5]) * sc;
    float v6 = (useP ? sp[6] : sn[6]) * sc, v7 = (useP ? sp[7] : sn[7]) * sc;
    uint4 o;
    o.x = pack2(v0, v1); o.y = pack2(v2, v3);
    o.z = pack2(v4, v5); o.w = pack2(v6, v7);
    ushort* dst = (g == 0) ? (pos2 + (long)node * 256 + l * 8)
                           : (neg2 + (long)node * 256 + ((l + 16) & 31) * 8);
    *(uint4*)dst = o;
}

// ---------------- bf16 MFMA GEMM + tanh (z-fused pair, 2-phase, B-in-registers) ----------------
// 128x128 tile, BK=64. LDS holds ONLY the A double-buffer (32KB); B fragments are
// loaded straight from global (L2-hot weights) into registers, prefetched one
// compute-block ahead. 2-phase order: stage/loadB(next) before compute(cur).
template<int K, int OUTC, int W0, bool OUTF32>
__global__ __launch_bounds__(256) void mfma_gemm_tanh(
    const ushort* p0a, const ushort* p0b, int st0,
    const ushort* p1a, const ushort* p1b, int st1,
    const ushort* WTa, const ushort* WTb,
    const float* biasa, const float* biasb,
    void* outa, void* outb, int ostride, int M)
{
    const ushort* p0 = blockIdx.z ? p0b : p0a;
    const ushort* p1 = blockIdx.z ? p1b : p1a;
    const ushort* WT = blockIdx.z ? WTb : WTa;
    const float* bias = blockIdx.z ? biasb : biasa;
    void* outv = blockIdx.z ? outb : outa;

    __shared__ __align__(16) ushort S[16384];   // A0 | A1 (8192 each = 16KB each)

    int tid = threadIdx.x;
    int rowBase = blockIdx.x * 128;
    int colBase = blockIdx.y * 128;
    int w = tid >> 6, lane = tid & 63;
    int wr = (w >> 1) * 64, wc = (w & 1) * 64;
    int l15 = lane & 15;
    int lk = lane >> 4;
    int sr = lane >> 3;                    // staging row within 8-row unit
    int sc = (lane & 7) ^ sr;              // pre-swizzled global source chunk

    f32x4 acc[4][4] = {};
    constexpr int NTI = K / 64;

    auto stageA = [&](int t, ushort* Al) {
        int k0 = t * 64;
        const ushort* pA; int stA, kloc;
        if (k0 < W0) { pA = p0; stA = st0; kloc = k0; }
        else         { pA = p1; stA = st1; kloc = k0 - W0; }
#pragma unroll
        for (int i2 = 0; i2 < 4; i2++) {
            int u = w * 4 + i2;
            int r = u * 8 + sr;
            int grow = rowBase + r;
            if (grow >= M) grow = M - 1;
            gload16(pA + (long)grow * stA + kloc + sc * 8, Al + u * 512);
        }
    };
    auto loadB = [&](int t, int kk, short8* b) {
#pragma unroll
        for (int nn = 0; nn < 4; nn++)
            b[nn] = *(const short8*)(WT + (long)(colBase + wc + nn * 16 + l15) * K
                                        + t * 64 + (kk * 4 + lk) * 8);
    };
    auto computeKK = [&](const ushort* Al, int kk, const short8* b) {
        short8 af[4];
#pragma unroll
        for (int m = 0; m < 4; m++) {
            int rA = wr + m * 16 + l15;
            int ch = (kk * 4 + lk) ^ (rA & 7);
            af[m] = *(const short8*)&Al[rA * 64 + ch * 8];
        }
#pragma unroll
        for (int m = 0; m < 4; m++)
#pragma unroll
            for (int nn = 0; nn < 4; nn++)
                acc[m][nn] = __builtin_amdgcn_mfma_f32_16x16x32_bf16(
                    af[m], b[nn], acc[m][nn], 0, 0, 0);
    };

    short8 bA[4], bB[4];
    stageA(0, S);
    loadB(0, 0, bA);
    __syncthreads();                       // A0 ready
    for (int t = 0; t < NTI; t++) {
        ushort* Ac = (t & 1) ? S + 8192 : S;
        ushort* An = (t & 1) ? S : S + 8192;
        if (t + 1 < NTI) stageA(t + 1, An);   // async A-loads overlap compute
        loadB(t, 1, bB);                      // kk1 B-loads overlap computeKK0
        computeKK(Ac, 0, bA);
        if (t + 1 < NTI) loadB(t + 1, 0, bA); // next kk0 overlaps computeKK1
        computeKK(Ac, 1, bB);
        __syncthreads();                      // drain A-stage, flip buffers
    }

    if (!OUTF32) {
        // bf16 epilogue: two 64-row passes, LDS restage (stride 136) + uint4 stores
#pragma unroll
        for (int p = 0; p < 2; p++) {
            __syncthreads();
            if ((wr >> 6) == p) {
#pragma unroll
                for (int nn = 0; nn < 4; nn++) {
                    int cl = wc + nn * 16 + l15;
                    float bv = bias[colBase + cl];
#pragma unroll
                    for (int m = 0; m < 4; m++) {
#pragma unroll
                        for (int j = 0; j < 4; j++)
                            S[(m * 16 + lk * 4 + j) * 136 + cl] =
                                f2bf(tanhf(acc[m][nn][j] + bv));
                    }
                }
            }
            __syncthreads();
#pragma unroll
            for (int it = 0; it < 4; it++) {
                int idx = tid + it * 256;          // 64 rows x 16 chunks
                int r2 = idx >> 4, c2 = idx & 15;
                int grow = rowBase + p * 64 + r2;
                if (grow < M) {
                    uint4 v = *(const uint4*)&S[r2 * 136 + c2 * 8];
                    *(uint4*)((ushort*)outv + (long)grow * ostride + colBase + c2 * 8) = v;
                }
            }
        }
    } else {
        // fp32 epilogue: four 32-row passes (stride 132 floats)
        float* Sf = (float*)S;
#pragma unroll
        for (int p = 0; p < 4; p++) {
            __syncthreads();
            if ((wr >> 6) == (p >> 1)) {
#pragma unroll
                for (int nn = 0; nn < 4; nn++) {
                    int cl = wc + nn * 16 + l15;
                    float bv = bias[colBase + cl];
#pragma unroll
                    for (int mm = 0; mm < 2; mm++) {
                        int m = (p & 1) * 2 + mm;
#pragma unroll
                        for (int j = 0; j < 4; j++)
                            Sf[(mm * 16 + lk * 4 + j) * 132 + cl] =
                                tanhf(acc[m][nn][j] + bv);
                    }
                }
            }
            __syncthreads();
#pragma unroll
            for (int it = 0; it < 4; it++) {
                int idx = tid + it * 256;       // 32 rows x 32 float4-chunks
                int r2 = idx >> 5, c2 = idx & 31;
                int grow = rowBase + p * 32 + r2;
                if (grow < M) {
                    float4 v = *(const float4*)&Sf[r2 * 132 + c2 * 4];
                    *(float4*)((float*)outv + (long)grow * ostride + colBase + c2 * 4) = v;
                }
            }
        }
    }
}

extern "C" void kernel_launch(void* const* d_in, const int* in_sizes, int n_in,
                              void* d_out, int out_size, void* d_ws, size_t ws_size,
                              hipStream_t stream) {
    const float* x       = (const float*)d_in[0];
    const int*   pos_src = (const int*)d_in[1];
    const int*   pos_dst = (const int*)d_in[2];
    const int*   neg_src = (const int*)d_in[3];
    const int*   neg_dst = (const int*)d_in[4];
    const float* W_oneB  = (const float*)d_in[5];
    const float* b_oneB  = (const float*)d_in[6];
    const float* W_oneH  = (const float*)d_in[7];
    const float* b_oneH  = (const float*)d_in[8];
    const float* W_twoB  = (const float*)d_in[9];
    const float* b_twoB  = (const float*)d_in[10];
    const float* W_twoH  = (const float*)d_in[11];
    const float* b_twoH  = (const float*)d_in[12];
    const float* W_four  = (const float*)d_in[13];
    const float* b_four  = (const float*)d_in[14];

    const int D = in_sizes[6];        // 128
    const int N = in_sizes[0] / D;    // 50000  (< 65536 -> ushort perm ok)
    const int E = in_sizes[1];        // 800000

    ushort* wb = (ushort*)d_ws;
    size_t ND = (size_t)N * D;
    ushort* xb   = wb;
    ushort* mpn  = wb + ND;
    ushort* hbn2 = wb;
    ushort* hbn1 = wb + 4 * ND;
    ushort* pos2 = wb + 6 * ND;
    ushort* neg2 = wb + 8 * ND;
    ushort* wt1  = wb + 10 * ND;
    ushort* wt2  = wt1 + 2 * D * D;
    ushort* wt3  = wt2 + 2 * D * D;
    ushort* wt4  = wt3 + 6 * D * D;
    ushort* wt5  = wt4 + 6 * D * D;
    ushort* p_perm = wt5 + 4 * D * D;
    ushort* n_perm = p_perm + E;
    ushort* p_rank = n_perm + E;
    ushort* n_rank = p_rank + E;
    int* ip    = (int*)(n_rank + E);
    int* p_row = ip;
    int* n_row = ip + (N + 1);

    int gridE  = (E + THREADS - 1) / THREADS;
    long n8    = (long)ND / 8;
    int cvtB   = (int)((n8 + THREADS - 1) / THREADS);
    int trB    = (20 * D * D + THREADS - 1) / THREADS;
    int gridN4 = (N + 3) / 4;
    int gx = (N + 127) / 128;
    dim3 g1(gx, 1, 2), g2(gx, 2, 2), g3(gx, 1, 1);

    // CSR build + conversions (fused)
    hipMemsetAsync(ip, 0, 2 * (size_t)(N + 1) * sizeof(int), stream);
    count_convert<<<gridE + cvtB, THREADS, 0, stream>>>(
        pos_dst, neg_dst, p_row, n_row, p_rank, n_rank, E, gridE, x, xb, n8);
    scan2_kernel<<<2, 1024, 0, stream>>>(p_row, n_row, N);
    fill_transpose<<<gridE + trB, THREADS, 0, stream>>>(
        pos_src, pos_dst, neg_src, neg_dst, p_row, n_row, p_rank, n_rank,
        p_perm, n_perm, E, gridE,
        W_oneB, wt1, W_oneH, wt2, W_twoB, wt3, W_twoH, wt4, W_four, wt5, D);

    // layer 1
    gather_l1<<<gridN4, THREADS, 0, stream>>>(p_row, n_row, p_perm, n_perm, xb, mpn, N);
    mfma_gemm_tanh<256, 128, 128, false><<<g1, THREADS, 0, stream>>>(
        mpn, mpn + 128, 256, xb, xb, 128,
        wt1, wt2, b_oneB, b_oneH, hbn1, hbn1 + 128, 256, N);

    // layer 2
    gather_l2<<<gridN4, THREADS, 0, stream>>>(p_row, n_row, p_perm, n_perm,
                                              hbn1, pos2, neg2, N);
    mfma_gemm_tanh<384, 256, 256, false><<<g2, THREADS, 0, stream>>>(
        pos2, neg2, 256, hbn1, hbn1 + 128, 256,
        wt3, wt4, b_twoB, b_twoH, hbn2, hbn2 + 256, 512, N);

    // final
    mfma_gemm_tanh<512, 128, 512, true><<<g3, THREADS, 0, stream>>>(
        hbn2, hbn2, 512, hbn2, hbn2, 512,
        wt5, wt5, b_four, b_four, d_out, d_out, 128, N);
}

// Round 9
// 535.398 us; speedup vs baseline: 1.1629x; 1.1629x over previous
//
#include <hip/hip_runtime.h>
#include <math.h>

#define THREADS 256

typedef __attribute__((ext_vector_type(8))) short short8;
typedef __attribute__((ext_vector_type(4))) float f32x4;

static __device__ __forceinline__ ushort f2bf(float f) {
    uint u = __float_as_uint(f);
    uint r = (u + 0x7FFFu + ((u >> 16) & 1u)) >> 16;   // RNE
    return (ushort)r;
}
static __device__ __forceinline__ float bf2f(ushort h) {
    return __uint_as_float(((uint)h) << 16);
}
static __device__ __forceinline__ uint pack2(float a, float b) {
    return (uint)f2bf(a) | ((uint)f2bf(b) << 16);
}
// async global->LDS, 16B per lane; LDS dest = wave-uniform base + lane*16
static __device__ __forceinline__ void gload16(const ushort* g, ushort* l) {
    __builtin_amdgcn_global_load_lds(
        (const __attribute__((address_space(1))) void*)g,
        (__attribute__((address_space(3))) void*)l, 16, 0, 0);
}
// accumulate 8 bf16 (as uint4) into 8 fp32
static __device__ __forceinline__ void acc8(float* s, uint4 v) {
    s[0] += bf2f((ushort)v.x); s[1] += bf2f((ushort)(v.x >> 16));
    s[2] += bf2f((ushort)v.y); s[3] += bf2f((ushort)(v.y >> 16));
    s[4] += bf2f((ushort)v.z); s[5] += bf2f((ushort)(v.z >> 16));
    s[6] += bf2f((ushort)v.w); s[7] += bf2f((ushort)(v.w >> 16));
}

// ---------------- fused CSR-count + x->bf16 convert ----------------
__global__ void count_convert(const int* __restrict__ pdst, const int* __restrict__ ndst,
                              int* pcnt, int* ncnt,
                              ushort* __restrict__ prank, ushort* __restrict__ nrank,
                              int E, int cblk,
                              const float* __restrict__ x, ushort* __restrict__ xb, long n8) {
    if ((int)blockIdx.x < cblk) {
        int e = blockIdx.x * blockDim.x + threadIdx.x;
        if (e < E) {
            prank[e] = (ushort)atomicAdd(&pcnt[pdst[e]], 1);
            nrank[e] = (ushort)atomicAdd(&ncnt[ndst[e]], 1);
        }
    } else {
        long o = (long)(blockIdx.x - cblk) * blockDim.x + threadIdx.x;
        if (o < n8) {
            long base = o * 8;
            float4 f0 = *(const float4*)(x + base);
            float4 f1 = *(const float4*)(x + base + 4);
            uint4 u;
            u.x = pack2(f0.x, f0.y);
            u.y = pack2(f0.z, f0.w);
            u.z = pack2(f1.x, f1.y);
            u.w = pack2(f1.z, f1.w);
            *(uint4*)(xb + base) = u;
        }
    }
}

// two independent in-place exclusive scans (block 0 -> a, block 1 -> b); rp[n]=total
__global__ __launch_bounds__(1024) void scan2_kernel(int* a, int* b, int n) {
    int* rp = blockIdx.x ? b : a;
    __shared__ int sums[1024];
    int t = threadIdx.x;
    int ch = (n + 1023) >> 10;
    int beg = t * ch;
    int end = min(beg + ch, n);
    int s = 0;
    for (int i = beg; i < end; i++) s += rp[i];
    sums[t] = s;
    __syncthreads();
    for (int off = 1; off < 1024; off <<= 1) {
        int v = (t >= off) ? sums[t - off] : 0;
        __syncthreads();
        sums[t] += v;
        __syncthreads();
    }
    int run = (t > 0) ? sums[t - 1] : 0;
    for (int i = beg; i < end; i++) {
        int c = rp[i];
        rp[i] = run;
        run += c;
    }
    if (t == 1023) rp[n] = sums[1023];
}

// ---------------- fused CSR-fill + weight transpose ----------------
__global__ void fill_transpose(const int* __restrict__ psrc, const int* __restrict__ pdst,
                               const int* __restrict__ nsrc, const int* __restrict__ ndst,
                               const int* __restrict__ prow, const int* __restrict__ nrow,
                               const ushort* __restrict__ prank, const ushort* __restrict__ nrank,
                               ushort* __restrict__ pperm, ushort* __restrict__ nperm,
                               int E, int fblk,
                               const float* W1, ushort* T1, const float* W2, ushort* T2,
                               const float* W3, ushort* T3, const float* W4, ushort* T4,
                               const float* W5, ushort* T5, int D) {
    if ((int)blockIdx.x < fblk) {
        int e = blockIdx.x * blockDim.x + threadIdx.x;
        if (e < E) {
            pperm[prow[pdst[e]] + prank[e]] = (ushort)psrc[e];
            nperm[nrow[ndst[e]] + nrank[e]] = (ushort)nsrc[e];
        }
    } else {
        int o = (blockIdx.x - fblk) * blockDim.x + threadIdx.x;
        int s1 = 2 * D * D, s3 = 6 * D * D, s5 = 4 * D * D;
        const float* W; ushort* T; int K, C;
        int off = o;
        if (off < s1)              { W = W1; T = T1; K = 2 * D; C = D; }
        else if ((off -= s1) < s1) { W = W2; T = T2; K = 2 * D; C = D; }
        else if ((off -= s1) < s3) { W = W3; T = T3; K = 3 * D; C = 2 * D; }
        else if ((off -= s3) < s3) { W = W4; T = T4; K = 3 * D; C = 2 * D; }
        else if ((off -= s3) < s5) { W = W5; T = T5; K = 4 * D; C = D; }
        else return;
        int c = off / K, k = off - c * K;
        T[off] = f2bf(W[(long)k * C + c]);
    }
}

// ---------------- gathers: 1 node/wave, uint4 loads, pos/neg interleaved ----------------
// layer 1: 4 edge-groups x 16 lanes (16B/lane covers the 256B row)
__global__ __launch_bounds__(256) void gather_l1(
        const int* __restrict__ p_row, const int* __restrict__ n_row,
        const ushort* __restrict__ p_perm, const ushort* __restrict__ n_perm,
        const ushort* __restrict__ xb, ushort* __restrict__ mpn, int n) {
    int node = blockIdx.x * 4 + (threadIdx.x >> 6);
    if (node >= n) return;
    int lane = threadIdx.x & 63;
    int g = lane >> 4, l = lane & 15;
    const ushort* rb = xb + l * 8;

    float sp[8] = {0,0,0,0,0,0,0,0}, sn[8] = {0,0,0,0,0,0,0,0};

    int i = p_row[node], ep = p_row[node + 1];
    int j = n_row[node], en = n_row[node + 1];
    float invp = 1.0f / (float)max(ep - i, 1);
    float invn = 1.0f / (float)max(en - j, 1);

    // main: both signs in flight (4 uint4 outstanding per lane)
    while (i + 8 <= ep && j + 8 <= en) {
        uint4 a0 = *(const uint4*)(rb + (long)p_perm[i + g] * 128);
        uint4 a1 = *(const uint4*)(rb + (long)p_perm[i + 4 + g] * 128);
        uint4 c0 = *(const uint4*)(rb + (long)n_perm[j + g] * 128);
        uint4 c1 = *(const uint4*)(rb + (long)n_perm[j + 4 + g] * 128);
        acc8(sp, a0); acc8(sp, a1); acc8(sn, c0); acc8(sn, c1);
        i += 8; j += 8;
    }
    for (; i + 8 <= ep; i += 8) {
        uint4 a0 = *(const uint4*)(rb + (long)p_perm[i + g] * 128);
        uint4 a1 = *(const uint4*)(rb + (long)p_perm[i + 4 + g] * 128);
        acc8(sp, a0); acc8(sp, a1);
    }
    for (; i + g < ep; i += 4) {
        uint4 a0 = *(const uint4*)(rb + (long)p_perm[i + g] * 128);
        acc8(sp, a0);
    }
    for (; j + 8 <= en; j += 8) {
        uint4 c0 = *(const uint4*)(rb + (long)n_perm[j + g] * 128);
        uint4 c1 = *(const uint4*)(rb + (long)n_perm[j + 4 + g] * 128);
        acc8(sn, c0); acc8(sn, c1);
    }
    for (; j + g < en; j += 4) {
        uint4 c0 = *(const uint4*)(rb + (long)n_perm[j + g] * 128);
        acc8(sn, c0);
    }

#pragma unroll
    for (int q = 0; q < 8; q++) {
        sp[q] += __shfl_xor(sp[q], 16);
        sp[q] += __shfl_xor(sp[q], 32);
        sn[q] += __shfl_xor(sn[q], 16);
        sn[q] += __shfl_xor(sn[q], 32);
    }

    if (g == 0) {
        uint4 o;
        o.x = pack2(sp[0] * invp, sp[1] * invp);
        o.y = pack2(sp[2] * invp, sp[3] * invp);
        o.z = pack2(sp[4] * invp, sp[5] * invp);
        o.w = pack2(sp[6] * invp, sp[7] * invp);
        *(uint4*)(mpn + (long)node * 256 + l * 8) = o;
    } else if (g == 1) {
        uint4 o;
        o.x = pack2(sn[0] * invn, sn[1] * invn);
        o.y = pack2(sn[2] * invn, sn[3] * invn);
        o.z = pack2(sn[4] * invn, sn[5] * invn);
        o.w = pack2(sn[6] * invn, sn[7] * invn);
        *(uint4*)(mpn + (long)node * 256 + 128 + l * 8) = o;
    }
}

// layer 2: 2 edge-groups x 32 lanes (16B/lane covers the 512B [hb1|hn1] row)
__global__ __launch_bounds__(256) void gather_l2(
        const int* __restrict__ p_row, const int* __restrict__ n_row,
        const ushort* __restrict__ p_perm, const ushort* __restrict__ n_perm,
        const ushort* __restrict__ hbn1,
        ushort* __restrict__ pos2, ushort* __restrict__ neg2, int n) {
    int node = blockIdx.x * 4 + (threadIdx.x >> 6);
    if (node >= n) return;
    int lane = threadIdx.x & 63;
    int g = lane >> 5, l = lane & 31;
    const ushort* rb = hbn1 + l * 8;

    float sp[8] = {0,0,0,0,0,0,0,0}, sn[8] = {0,0,0,0,0,0,0,0};

    int i = p_row[node], ep = p_row[node + 1];
    int j = n_row[node], en = n_row[node + 1];
    float invp = 1.0f / (float)max(ep - i, 1);
    float invn = 1.0f / (float)max(en - j, 1);

    while (i + 4 <= ep && j + 4 <= en) {
        uint4 a0 = *(const uint4*)(rb + (long)p_perm[i + g] * 256);
        uint4 a1 = *(const uint4*)(rb + (long)p_perm[i + 2 + g] * 256);
        uint4 c0 = *(const uint4*)(rb + (long)n_perm[j + g] * 256);
        uint4 c1 = *(const uint4*)(rb + (long)n_perm[j + 2 + g] * 256);
        acc8(sp, a0); acc8(sp, a1); acc8(sn, c0); acc8(sn, c1);
        i += 4; j += 4;
    }
    for (; i + 4 <= ep; i += 4) {
        uint4 a0 = *(const uint4*)(rb + (long)p_perm[i + g] * 256);
        uint4 a1 = *(const uint4*)(rb + (long)p_perm[i + 2 + g] * 256);
        acc8(sp, a0); acc8(sp, a1);
    }
    for (; i + g < ep; i += 2) {
        uint4 a0 = *(const uint4*)(rb + (long)p_perm[i + g] * 256);
        acc8(sp, a0);
    }
    for (; j + 4 <= en; j += 4) {
        uint4 c0 = *(const uint4*)(rb + (long)n_perm[j + g] * 256);
        uint4 c1 = *(const uint4*)(rb + (long)n_perm[j + 2 + g] * 256);
        acc8(sn, c0); acc8(sn, c1);
    }
    for (; j + g < en; j += 2) {
        uint4 c0 = *(const uint4*)(rb + (long)n_perm[j + g] * 256);
        acc8(sn, c0);
    }

#pragma unroll
    for (int q = 0; q < 8; q++) {
        sp[q] += __shfl_xor(sp[q], 32);
        sn[q] += __shfl_xor(sn[q], 32);
    }

    // pos2[node] = [mean_pos(hb1) | mean_neg(hn1)]
    // neg2[node] = [mean_pos(hn1) | mean_neg(hb1)]
    bool useP = (g == 0) ? (l < 16) : (l >= 16);
    float sc = useP ? invp : invn;
    float v0 = (useP ? sp[0] : sn[0]) * sc, v1 = (useP ? sp[1] : sn[1]) * sc;
    float v2 = (useP ? sp[2] : sn[2]) * sc, v3 = (useP ? sp[3] : sn[3]) * sc;
    float v4 = (useP ? sp[4] : sn[4]) * sc, v5 = (useP ? sp[5] : sn[5]) * sc;
    float v6 = (useP ? sp[6] : sn[6]) * sc, v7 = (useP ? sp[7] : sn[7]) * sc;
    uint4 o;
    o.x = pack2(v0, v1); o.y = pack2(v2, v3);
    o.z = pack2(v4, v5); o.w = pack2(v6, v7);
    ushort* dst = (g == 0) ? (pos2 + (long)node * 256 + l * 8)
                           : (neg2 + (long)node * 256 + ((l + 16) & 31) * 8);
    *(uint4*)dst = o;
}

// ---------------- bf16 MFMA GEMM + tanh (z-fused pair, depth-3 ring pipeline) ----------------
// 128x128 tile, BK=32, 4-buffer LDS ring (A|B 8KB each, 64KB total).
// Loop: waitcnt vmcnt(8) [two newer stages stay in flight] -> s_barrier ->
//       stage(t+3) -> compute(t).  Tile-t loads issued 3 tiles ahead.
// LDS swizzle: slot (row, c) holds global chunk c ^ ((row>>1)&3); reader uses
// ch = lk ^ ((row>>1)&3) -> 2-way bank alias (free). Source pre-swizzled:
// lane chunk = (lane&3) ^ ((lane>>3)&3).
template<int K, int OUTC, int W0, bool OUTF32>
__global__ __launch_bounds__(256) void mfma_gemm_tanh(
    const ushort* p0a, const ushort* p0b, int st0,
    const ushort* p1a, const ushort* p1b, int st1,
    const ushort* WTa, const ushort* WTb,
    const float* biasa, const float* biasb,
    void* outa, void* outb, int ostride, int M)
{
    const ushort* p0 = blockIdx.z ? p0b : p0a;
    const ushort* p1 = blockIdx.z ? p1b : p1a;
    const ushort* WT = blockIdx.z ? WTb : WTa;
    const float* bias = blockIdx.z ? biasb : biasa;
    void* outv = blockIdx.z ? outb : outa;

    __shared__ __align__(16) ushort S[32768];   // 4 ring slots x [A 4096 | B 4096]

    int tid = threadIdx.x;
    int rowBase = blockIdx.x * 128;
    int colBase = blockIdx.y * 128;
    int w = tid >> 6, lane = tid & 63;
    int wr = (w >> 1) * 64, wc = (w & 1) * 64;
    int l15 = lane & 15;
    int lk = lane >> 4;
    int srow = lane >> 2;                        // row within 16-row unit
    int scl = (lane & 3) ^ ((lane >> 3) & 3);    // pre-swizzled source chunk

    f32x4 acc[4][4] = {};
    constexpr int NTI = K / 32;

    auto stage = [&](int t) {
        ushort* Al = S + (t & 3) * 8192;
        ushort* Bl = Al + 4096;
        int k0 = t * 32;
        const ushort* pA; int stA, kloc;
        if (k0 < W0) { pA = p0; stA = st0; kloc = k0; }
        else         { pA = p1; stA = st1; kloc = k0 - W0; }
#pragma unroll
        for (int i2 = 0; i2 < 2; i2++) {
            int u = w * 2 + i2;                  // unit: 16 rows x 4 chunks = 1KB
            int r = u * 16 + srow;
            int grow = rowBase + r;
            if (grow >= M) grow = M - 1;
            gload16(pA + (long)grow * stA + kloc + scl * 8, Al + u * 512);
            gload16(WT + (long)(colBase + r) * K + k0 + scl * 8, Bl + u * 512);
        }
    };
    auto compute = [&](int t) {
        const ushort* Al = S + (t & 3) * 8192;
        const ushort* Bl = Al + 4096;
        short8 af[4], bfr[4];
#pragma unroll
        for (int m = 0; m < 4; m++) {
            int rA = wr + m * 16 + l15;
            int ch = lk ^ ((rA >> 1) & 3);
            af[m] = *(const short8*)&Al[rA * 32 + ch * 8];
        }
#pragma unroll
        for (int nn = 0; nn < 4; nn++) {
            int rB = wc + nn * 16 + l15;
            int ch = lk ^ ((rB >> 1) & 3);
            bfr[nn] = *(const short8*)&Bl[rB * 32 + ch * 8];
        }
#pragma unroll
        for (int m = 0; m < 4; m++)
#pragma unroll
            for (int nn = 0; nn < 4; nn++)
                acc[m][nn] = __builtin_amdgcn_mfma_f32_16x16x32_bf16(
                    af[m], bfr[nn], acc[m][nn], 0, 0, 0);
    };

    stage(0); stage(1); stage(2);                // depth-3 prologue (12 loads/wave)
#pragma unroll
    for (int t = 0; t < NTI; t++) {
        // wait for OWN tile-t loads only: 2 newer stages (8 loads) may stay in flight
        if (t + 2 < NTI)      asm volatile("s_waitcnt vmcnt(8)" ::: "memory");
        else if (t + 1 < NTI) asm volatile("s_waitcnt vmcnt(4)" ::: "memory");
        else                  asm volatile("s_waitcnt vmcnt(0)" ::: "memory");
        __builtin_amdgcn_s_barrier();            // all waves' tile-t DMA complete
        __builtin_amdgcn_sched_barrier(0);       // pin: no ds_read hoists above
        if (t + 3 < NTI) stage(t + 3);           // overwrites buf (t-1)&3: safe post-barrier
        compute(t);
    }
    __syncthreads();                             // full drain before S reuse

    if (!OUTF32) {
        // bf16 epilogue: LDS restage (stride 136) + coalesced uint4 stores
#pragma unroll
        for (int nn = 0; nn < 4; nn++) {
            int cl = wc + nn * 16 + l15;
            float bv = bias[colBase + cl];
#pragma unroll
            for (int m = 0; m < 4; m++) {
                int rl = wr + m * 16 + lk * 4;
#pragma unroll
                for (int j = 0; j < 4; j++)
                    S[(rl + j) * 136 + cl] = f2bf(tanhf(acc[m][nn][j] + bv));
            }
        }
        __syncthreads();
#pragma unroll
        for (int it = 0; it < 8; it++) {
            int idx = tid + it * 256;          // 128 rows x 16 chunks
            int r2 = idx >> 4, c2 = idx & 15;
            int grow = rowBase + r2;
            if (grow < M) {
                uint4 v = *(const uint4*)&S[r2 * 136 + c2 * 8];
                *(uint4*)((ushort*)outv + (long)grow * ostride + colBase + c2 * 8) = v;
            }
        }
    } else {
        // fp32 epilogue: two half-tiles of 64 rows (stride 132 floats)
        float* Sf = (float*)S;
#pragma unroll
        for (int p = 0; p < 2; p++) {
            if (p) __syncthreads();
            if ((wr >> 6) == p) {
#pragma unroll
                for (int nn = 0; nn < 4; nn++) {
                    int cl = wc + nn * 16 + l15;
                    float bv = bias[colBase + cl];
#pragma unroll
                    for (int m = 0; m < 4; m++) {
                        int rl = m * 16 + lk * 4;
#pragma unroll
                        for (int j = 0; j < 4; j++)
                            Sf[(rl + j) * 132 + cl] = tanhf(acc[m][nn][j] + bv);
                    }
                }
            }
            __syncthreads();
#pragma unroll
            for (int it = 0; it < 8; it++) {
                int idx = tid + it * 256;       // 64 rows x 32 float4-chunks
                int r2 = idx >> 5, c2 = idx & 31;
                int grow = rowBase + p * 64 + r2;
                if (grow < M) {
                    float4 v = *(const float4*)&Sf[r2 * 132 + c2 * 4];
                    *(float4*)((float*)outv + (long)grow * ostride + colBase + c2 * 4) = v;
                }
            }
        }
    }
}

extern "C" void kernel_launch(void* const* d_in, const int* in_sizes, int n_in,
                              void* d_out, int out_size, void* d_ws, size_t ws_size,
                              hipStream_t stream) {
    const float* x       = (const float*)d_in[0];
    const int*   pos_src = (const int*)d_in[1];
    const int*   pos_dst = (const int*)d_in[2];
    const int*   neg_src = (const int*)d_in[3];
    const int*   neg_dst = (const int*)d_in[4];
    const float* W_oneB  = (const float*)d_in[5];
    const float* b_oneB  = (const float*)d_in[6];
    const float* W_oneH  = (const float*)d_in[7];
    const float* b_oneH  = (const float*)d_in[8];
    const float* W_twoB  = (const float*)d_in[9];
    const float* b_twoB  = (const float*)d_in[10];
    const float* W_twoH  = (const float*)d_in[11];
    const float* b_twoH  = (const float*)d_in[12];
    const float* W_four  = (const float*)d_in[13];
    const float* b_four  = (const float*)d_in[14];

    const int D = in_sizes[6];        // 128
    const int N = in_sizes[0] / D;    // 50000  (< 65536 -> ushort perm ok)
    const int E = in_sizes[1];        // 800000

    ushort* wb = (ushort*)d_ws;
    size_t ND = (size_t)N * D;
    ushort* xb   = wb;
    ushort* mpn  = wb + ND;
    ushort* hbn2 = wb;
    ushort* hbn1 = wb + 4 * ND;
    ushort* pos2 = wb + 6 * ND;
    ushort* neg2 = wb + 8 * ND;
    ushort* wt1  = wb + 10 * ND;
    ushort* wt2  = wt1 + 2 * D * D;
    ushort* wt3  = wt2 + 2 * D * D;
    ushort* wt4  = wt3 + 6 * D * D;
    ushort* wt5  = wt4 + 6 * D * D;
    ushort* p_perm = wt5 + 4 * D * D;
    ushort* n_perm = p_perm + E;
    ushort* p_rank = n_perm + E;
    ushort* n_rank = p_rank + E;
    int* ip    = (int*)(n_rank + E);
    int* p_row = ip;
    int* n_row = ip + (N + 1);

    int gridE  = (E + THREADS - 1) / THREADS;
    long n8    = (long)ND / 8;
    int cvtB   = (int)((n8 + THREADS - 1) / THREADS);
    int trB    = (20 * D * D + THREADS - 1) / THREADS;
    int gridN4 = (N + 3) / 4;
    int gx = (N + 127) / 128;
    dim3 g1(gx, 1, 2), g2(gx, 2, 2), g3(gx, 1, 1);

    // CSR build + conversions (fused)
    hipMemsetAsync(ip, 0, 2 * (size_t)(N + 1) * sizeof(int), stream);
    count_convert<<<gridE + cvtB, THREADS, 0, stream>>>(
        pos_dst, neg_dst, p_row, n_row, p_rank, n_rank, E, gridE, x, xb, n8);
    scan2_kernel<<<2, 1024, 0, stream>>>(p_row, n_row, N);
    fill_transpose<<<gridE + trB, THREADS, 0, stream>>>(
        pos_src, pos_dst, neg_src, neg_dst, p_row, n_row, p_rank, n_rank,
        p_perm, n_perm, E, gridE,
        W_oneB, wt1, W_oneH, wt2, W_twoB, wt3, W_twoH, wt4, W_four, wt5, D);

    // layer 1
    gather_l1<<<gridN4, THREADS, 0, stream>>>(p_row, n_row, p_perm, n_perm, xb, mpn, N);
    mfma_gemm_tanh<256, 128, 128, false><<<g1, THREADS, 0, stream>>>(
        mpn, mpn + 128, 256, xb, xb, 128,
        wt1, wt2, b_oneB, b_oneH, hbn1, hbn1 + 128, 256, N);

    // layer 2
    gather_l2<<<gridN4, THREADS, 0, stream>>>(p_row, n_row, p_perm, n_perm,
                                              hbn1, pos2, neg2, N);
    mfma_gemm_tanh<384, 256, 256, false><<<g2, THREADS, 0, stream>>>(
        pos2, neg2, 256, hbn1, hbn1 + 128, 256,
        wt3, wt4, b_twoB, b_twoH, hbn2, hbn2 + 256, 512, N);

    // final
    mfma_gemm_tanh<512, 128, 512, true><<<g3, THREADS, 0, stream>>>(
        hbn2, hbn2, 512, hbn2, hbn2, 512,
        wt5, wt5, b_four, b_four, d_out, d_out, 128, N);
}

// Round 12
// 411.801 us; speedup vs baseline: 1.5119x; 1.3001x over previous
//
#include <hip/hip_runtime.h>
#include <math.h>

#define THREADS 256

typedef __attribute__((ext_vector_type(8))) short short8;
typedef __attribute__((ext_vector_type(4))) float f32x4;

static __device__ __forceinline__ ushort f2bf(float f) {
    uint u = __float_as_uint(f);
    uint r = (u + 0x7FFFu + ((u >> 16) & 1u)) >> 16;   // RNE
    return (ushort)r;
}
static __device__ __forceinline__ float bf2f(ushort h) {
    return __uint_as_float(((uint)h) << 16);
}
static __device__ __forceinline__ uint pack2(float a, float b) {
    return (uint)f2bf(a) | ((uint)f2bf(b) << 16);
}
// fast tanh: 1 - 2/(e^2x + 1); exp2-based, ~5 VALU ops, correct +-1 saturation
static __device__ __forceinline__ float fast_tanh(float x) {
    float e = __builtin_amdgcn_exp2f(x * 2.8853900817779268f);   // e^(2x)
    return fmaf(-2.0f, __builtin_amdgcn_rcpf(e + 1.0f), 1.0f);
}
// async global->LDS, 16B per lane; LDS dest = wave-uniform base + lane*16
static __device__ __forceinline__ void gload16(const ushort* g, ushort* l) {
    __builtin_amdgcn_global_load_lds(
        (const __attribute__((address_space(1))) void*)g,
        (__attribute__((address_space(3))) void*)l, 16, 0, 0);
}
// accumulate 8 bf16 (as uint4) into 8 fp32
static __device__ __forceinline__ void acc8(float* s, uint4 v) {
    s[0] += bf2f((ushort)v.x); s[1] += bf2f((ushort)(v.x >> 16));
    s[2] += bf2f((ushort)v.y); s[3] += bf2f((ushort)(v.y >> 16));
    s[4] += bf2f((ushort)v.z); s[5] += bf2f((ushort)(v.z >> 16));
    s[6] += bf2f((ushort)v.w); s[7] += bf2f((ushort)(v.w >> 16));
}

#define WAITV(n) asm volatile("s_waitcnt vmcnt(" #n ")" ::: "memory")

// ---------------- fused CSR-count + x->bf16 convert ----------------
__global__ void count_convert(const int* __restrict__ pdst, const int* __restrict__ ndst,
                              int* pcnt, int* ncnt,
                              ushort* __restrict__ prank, ushort* __restrict__ nrank,
                              int E, int cblk,
                              const float* __restrict__ x, ushort* __restrict__ xb, long n8) {
    if ((int)blockIdx.x < cblk) {
        int e = blockIdx.x * blockDim.x + threadIdx.x;
        if (e < E) {
            prank[e] = (ushort)atomicAdd(&pcnt[pdst[e]], 1);
            nrank[e] = (ushort)atomicAdd(&ncnt[ndst[e]], 1);
        }
    } else {
        long o = (long)(blockIdx.x - cblk) * blockDim.x + threadIdx.x;
        if (o < n8) {
            long base = o * 8;
            float4 f0 = *(const float4*)(x + base);
            float4 f1 = *(const float4*)(x + base + 4);
            uint4 u;
            u.x = pack2(f0.x, f0.y);
            u.y = pack2(f0.z, f0.w);
            u.z = pack2(f1.x, f1.y);
            u.w = pack2(f1.z, f1.w);
            *(uint4*)(xb + base) = u;
        }
    }
}

// two independent in-place exclusive scans (block 0 -> a, block 1 -> b); rp[n]=total
__global__ __launch_bounds__(1024) void scan2_kernel(int* a, int* b, int n) {
    int* rp = blockIdx.x ? b : a;
    __shared__ int sums[1024];
    int t = threadIdx.x;
    int ch = (n + 1023) >> 10;
    int beg = t * ch;
    int end = min(beg + ch, n);
    int s = 0;
    for (int i = beg; i < end; i++) s += rp[i];
    sums[t] = s;
    __syncthreads();
    for (int off = 1; off < 1024; off <<= 1) {
        int v = (t >= off) ? sums[t - off] : 0;
        __syncthreads();
        sums[t] += v;
        __syncthreads();
    }
    int run = (t > 0) ? sums[t - 1] : 0;
    for (int i = beg; i < end; i++) {
        int c = rp[i];
        rp[i] = run;
        run += c;
    }
    if (t == 1023) rp[n] = sums[1023];
}

// ---------------- fused CSR-fill + weight transpose ----------------
__global__ void fill_transpose(const int* __restrict__ psrc, const int* __restrict__ pdst,
                               const int* __restrict__ nsrc, const int* __restrict__ ndst,
                               const int* __restrict__ prow, const int* __restrict__ nrow,
                               const ushort* __restrict__ prank, const ushort* __restrict__ nrank,
                               ushort* __restrict__ pperm, ushort* __restrict__ nperm,
                               int E, int fblk,
                               const float* W1, ushort* T1, const float* W2, ushort* T2,
                               const float* W3, ushort* T3, const float* W4, ushort* T4,
                               const float* W5, ushort* T5, int D) {
    if ((int)blockIdx.x < fblk) {
        int e = blockIdx.x * blockDim.x + threadIdx.x;
        if (e < E) {
            pperm[prow[pdst[e]] + prank[e]] = (ushort)psrc[e];
            nperm[nrow[ndst[e]] + nrank[e]] = (ushort)nsrc[e];
        }
    } else {
        int o = (blockIdx.x - fblk) * blockDim.x + threadIdx.x;
        int s1 = 2 * D * D, s3 = 6 * D * D, s5 = 4 * D * D;
        const float* W; ushort* T; int K, C;
        int off = o;
        if (off < s1)              { W = W1; T = T1; K = 2 * D; C = D; }
        else if ((off -= s1) < s1) { W = W2; T = T2; K = 2 * D; C = D; }
        else if ((off -= s1) < s3) { W = W3; T = T3; K = 3 * D; C = 2 * D; }
        else if ((off -= s3) < s3) { W = W4; T = T4; K = 3 * D; C = 2 * D; }
        else if ((off -= s3) < s5) { W = W5; T = T5; K = 4 * D; C = D; }
        else return;
        int c = off / K, k = off - c * K;
        T[off] = f2bf(W[(long)k * C + c]);
    }
}

// ---------------- gathers: 1 node/wave, uint4 loads, pos/neg interleaved ----------------
// layer 1: 4 edge-groups x 16 lanes (16B/lane covers the 256B row)
__global__ __launch_bounds__(256) void gather_l1(
        const int* __restrict__ p_row, const int* __restrict__ n_row,
        const ushort* __restrict__ p_perm, const ushort* __restrict__ n_perm,
        const ushort* __restrict__ xb, ushort* __restrict__ mpn, int n) {
    int node = blockIdx.x * 4 + (threadIdx.x >> 6);
    if (node >= n) return;
    int lane = threadIdx.x & 63;
    int g = lane >> 4, l = lane & 15;
    const ushort* rb = xb + l * 8;

    float sp[8] = {0,0,0,0,0,0,0,0}, sn[8] = {0,0,0,0,0,0,0,0};

    int i = p_row[node], ep = p_row[node + 1];
    int j = n_row[node], en = n_row[node + 1];
    float invp = 1.0f / (float)max(ep - i, 1);
    float invn = 1.0f / (float)max(en - j, 1);

    while (i + 8 <= ep && j + 8 <= en) {
        uint4 a0 = *(const uint4*)(rb + (long)p_perm[i + g] * 128);
        uint4 a1 = *(const uint4*)(rb + (long)p_perm[i + 4 + g] * 128);
        uint4 c0 = *(const uint4*)(rb + (long)n_perm[j + g] * 128);
        uint4 c1 = *(const uint4*)(rb + (long)n_perm[j + 4 + g] * 128);
        acc8(sp, a0); acc8(sp, a1); acc8(sn, c0); acc8(sn, c1);
        i += 8; j += 8;
    }
    for (; i + 8 <= ep; i += 8) {
        uint4 a0 = *(const uint4*)(rb + (long)p_perm[i + g] * 128);
        uint4 a1 = *(const uint4*)(rb + (long)p_perm[i + 4 + g] * 128);
        acc8(sp, a0); acc8(sp, a1);
    }
    for (; i + g < ep; i += 4) {
        uint4 a0 = *(const uint4*)(rb + (long)p_perm[i + g] * 128);
        acc8(sp, a0);
    }
    for (; j + 8 <= en; j += 8) {
        uint4 c0 = *(const uint4*)(rb + (long)n_perm[j + g] * 128);
        uint4 c1 = *(const uint4*)(rb + (long)n_perm[j + 4 + g] * 128);
        acc8(sn, c0); acc8(sn, c1);
    }
    for (; j + g < en; j += 4) {
        uint4 c0 = *(const uint4*)(rb + (long)n_perm[j + g] * 128);
        acc8(sn, c0);
    }

#pragma unroll
    for (int q = 0; q < 8; q++) {
        sp[q] += __shfl_xor(sp[q], 16);
        sp[q] += __shfl_xor(sp[q], 32);
        sn[q] += __shfl_xor(sn[q], 16);
        sn[q] += __shfl_xor(sn[q], 32);
    }

    if (g == 0) {
        uint4 o;
        o.x = pack2(sp[0] * invp, sp[1] * invp);
        o.y = pack2(sp[2] * invp, sp[3] * invp);
        o.z = pack2(sp[4] * invp, sp[5] * invp);
        o.w = pack2(sp[6] * invp, sp[7] * invp);
        *(uint4*)(mpn + (long)node * 256 + l * 8) = o;
    } else if (g == 1) {
        uint4 o;
        o.x = pack2(sn[0] * invn, sn[1] * invn);
        o.y = pack2(sn[2] * invn, sn[3] * invn);
        o.z = pack2(sn[4] * invn, sn[5] * invn);
        o.w = pack2(sn[6] * invn, sn[7] * invn);
        *(uint4*)(mpn + (long)node * 256 + 128 + l * 8) = o;
    }
}

// layer 2: 2 edge-groups x 32 lanes (16B/lane covers the 512B [hb1|hn1] row)
__global__ __launch_bounds__(256) void gather_l2(
        const int* __restrict__ p_row, const int* __restrict__ n_row,
        const ushort* __restrict__ p_perm, const ushort* __restrict__ n_perm,
        const ushort* __restrict__ hbn1,
        ushort* __restrict__ pos2, ushort* __restrict__ neg2, int n) {
    int node = blockIdx.x * 4 + (threadIdx.x >> 6);
    if (node >= n) return;
    int lane = threadIdx.x & 63;
    int g = lane >> 5, l = lane & 31;
    const ushort* rb = hbn1 + l * 8;

    float sp[8] = {0,0,0,0,0,0,0,0}, sn[8] = {0,0,0,0,0,0,0,0};

    int i = p_row[node], ep = p_row[node + 1];
    int j = n_row[node], en = n_row[node + 1];
    float invp = 1.0f / (float)max(ep - i, 1);
    float invn = 1.0f / (float)max(en - j, 1);

    while (i + 4 <= ep && j + 4 <= en) {
        uint4 a0 = *(const uint4*)(rb + (long)p_perm[i + g] * 256);
        uint4 a1 = *(const uint4*)(rb + (long)p_perm[i + 2 + g] * 256);
        uint4 c0 = *(const uint4*)(rb + (long)n_perm[j + g] * 256);
        uint4 c1 = *(const uint4*)(rb + (long)n_perm[j + 2 + g] * 256);
        acc8(sp, a0); acc8(sp, a1); acc8(sn, c0); acc8(sn, c1);
        i += 4; j += 4;
    }
    for (; i + 4 <= ep; i += 4) {
        uint4 a0 = *(const uint4*)(rb + (long)p_perm[i + g] * 256);
        uint4 a1 = *(const uint4*)(rb + (long)p_perm[i + 2 + g] * 256);
        acc8(sp, a0); acc8(sp, a1);
    }
    for (; i + g < ep; i += 2) {
        uint4 a0 = *(const uint4*)(rb + (long)p_perm[i + g] * 256);
        acc8(sp, a0);
    }
    for (; j + 4 <= en; j += 4) {
        uint4 c0 = *(const uint4*)(rb + (long)n_perm[j + g] * 256);
        uint4 c1 = *(const uint4*)(rb + (long)n_perm[j + 2 + g] * 256);
        acc8(sn, c0); acc8(sn, c1);
    }
    for (; j + g < en; j += 2) {
        uint4 c0 = *(const uint4*)(rb + (long)n_perm[j + g] * 256);
        acc8(sn, c0);
    }

#pragma unroll
    for (int q = 0; q < 8; q++) {
        sp[q] += __shfl_xor(sp[q], 32);
        sn[q] += __shfl_xor(sn[q], 32);
    }

    // pos2[node] = [mean_pos(hb1) | mean_neg(hn1)]
    // neg2[node] = [mean_pos(hn1) | mean_neg(hb1)]
    bool useP = (g == 0) ? (l < 16) : (l >= 16);
    float sc = useP ? invp : invn;
    float v0 = (useP ? sp[0] : sn[0]) * sc, v1 = (useP ? sp[1] : sn[1]) * sc;
    float v2 = (useP ? sp[2] : sn[2]) * sc, v3 = (useP ? sp[3] : sn[3]) * sc;
    float v4 = (useP ? sp[4] : sn[4]) * sc, v5 = (useP ? sp[5] : sn[5]) * sc;
    float v6 = (useP ? sp[6] : sn[6]) * sc, v7 = (useP ? sp[7] : sn[7]) * sc;
    uint4 o;
    o.x = pack2(v0, v1); o.y = pack2(v2, v3);
    o.z = pack2(v4, v5); o.w = pack2(v6, v7);
    ushort* dst = (g == 0) ? (pos2 + (long)node * 256 + l * 8)
                           : (neg2 + (long)node * 256 + ((l + 16) & 31) * 8);
    *(uint4*)dst = o;
}

// ---------------- bf16 MFMA GEMM + tanh (depth-3 ring [verified r9] + XCD grouping) -------
// 128x128 tile, BK=32, 4-slot LDS ring. Slot = A(8KB) + B(8KB) = 16KB; 4 slots = 64KB
// exactly (round-10/11 bug: 6 slots = 96KB > 64KB -> OOB LDS -> deterministic corruption).
// T4 ladder: vmcnt(4 * min(2, NTI-1-t)) -> s_barrier -> stage(t+3) -> compute(t).
// 1-D grid, variant-inner logical ids + bijective XCD swizzle (m204): the NV variants
// of one row-tile get consecutive wgid -> same XCD chunk -> shared A rows are L2-hits.
template<int K, int OUTC, int W0, bool OUTF32, int NV>
__global__ __launch_bounds__(256) void mfma_gemm_tanh(
    const ushort* p0a, const ushort* p0b, int st0,
    const ushort* p1a, const ushort* p1b, int st1,
    const ushort* WTa, const ushort* WTb,
    const float* biasa, const float* biasb,
    void* outa, void* outb, int ostride, int M)
{
    // --- bijective XCD swizzle: dispatch id -> logical block id ---
    int nblk = gridDim.x;
    int d = blockIdx.x;
    int q = nblk >> 3, r = nblk & 7;
    int xcd = d & 7, base = d >> 3;
    int wgid = (xcd < r ? xcd * (q + 1) : r * (q + 1) + (xcd - r) * q) + base;
    int var = (NV > 1) ? (wgid % NV) : 0;
    int rt  = (NV > 1) ? (wgid / NV) : wgid;
    int zi  = (NV > 1) ? (var & 1) : 0;
    int rowBase = rt * 128;
    int colBase = (NV == 4) ? (var >> 1) * 128 : 0;

    const ushort* p0 = zi ? p0b : p0a;
    const ushort* p1 = zi ? p1b : p1a;
    const ushort* WT = zi ? WTb : WTa;
    const float* bias = zi ? biasb : biasa;
    void* outv = zi ? outb : outa;

    __shared__ __align__(16) ushort S[32768];   // 4 ring slots x [A 4096 | B 4096] = 64KB

    int tid = threadIdx.x;
    int w = tid >> 6, lane = tid & 63;
    int wr = (w >> 1) * 64, wc = (w & 1) * 64;
    int l15 = lane & 15;
    int lk = lane >> 4;
    int srow = lane >> 2;                        // row within 16-row unit
    int scl = (lane & 3) ^ ((lane >> 3) & 3);    // pre-swizzled source chunk

    f32x4 acc[4][4] = {};
    constexpr int NTI = K / 32;

    auto stage = [&](int t) {
        ushort* Al = S + (t & 3) * 8192;
        ushort* Bl = Al + 4096;
        int k0 = t * 32;
        const ushort* pA; int stA, kloc;
        if (k0 < W0) { pA = p0; stA = st0; kloc = k0; }
        else         { pA = p1; stA = st1; kloc = k0 - W0; }
#pragma unroll
        for (int i2 = 0; i2 < 2; i2++) {
            int u = w * 2 + i2;                  // unit: 16 rows x 4 chunks = 1KB
            int rr = u * 16 + srow;
            int grow = rowBase + rr;
            if (grow >= M) grow = M - 1;
            gload16(pA + (long)grow * stA + kloc + scl * 8, Al + u * 512);
            gload16(WT + (long)(colBase + rr) * K + k0 + scl * 8, Bl + u * 512);
        }
    };
    auto compute = [&](int t) {
        const ushort* Al = S + (t & 3) * 8192;
        const ushort* Bl = Al + 4096;
        short8 af[4], bfr[4];
#pragma unroll
        for (int m = 0; m < 4; m++) {
            int rA = wr + m * 16 + l15;
            int ch = lk ^ ((rA >> 1) & 3);
            af[m] = *(const short8*)&Al[rA * 32 + ch * 8];
        }
#pragma unroll
        for (int nn = 0; nn < 4; nn++) {
            int rB = wc + nn * 16 + l15;
            int ch = lk ^ ((rB >> 1) & 3);
            bfr[nn] = *(const short8*)&Bl[rB * 32 + ch * 8];
        }
#pragma unroll
        for (int m = 0; m < 4; m++)
#pragma unroll
            for (int nn = 0; nn < 4; nn++)
                acc[m][nn] = __builtin_amdgcn_mfma_f32_16x16x32_bf16(
                    af[m], bfr[nn], acc[m][nn], 0, 0, 0);
    };

    stage(0); stage(1); stage(2);                // depth-3 prologue (12 loads/wave)
#pragma unroll
    for (int t = 0; t < NTI; t++) {
        // newer stages still allowed in flight: min(2, NTI-1-t); 4 loads each
        int nf = NTI - 1 - t; if (nf > 2) nf = 2;
        switch (nf) {
            case 2: WAITV(8); break;
            case 1: WAITV(4); break;
            default: WAITV(0); break;
        }
        __builtin_amdgcn_s_barrier();            // all waves' tile-t DMA complete
        __builtin_amdgcn_sched_barrier(0);       // no ds_read hoists above barrier
        if (t + 3 < NTI) stage(t + 3);           // writes slot (t+3)&3 = (t-1)&3: freed
        compute(t);
    }
    __syncthreads();                             // cross-wave: all LDS reads done before reuse

    if (!OUTF32) {
        // bf16 epilogue: LDS restage (stride 136) + coalesced uint4 stores
#pragma unroll
        for (int nn = 0; nn < 4; nn++) {
            int cl = wc + nn * 16 + l15;
            float bv = bias[colBase + cl];
#pragma unroll
            for (int m = 0; m < 4; m++) {
                int rl = wr + m * 16 + lk * 4;
#pragma unroll
                for (int j = 0; j < 4; j++)
                    S[(rl + j) * 136 + cl] = f2bf(fast_tanh(acc[m][nn][j] + bv));
            }
        }
        __syncthreads();
#pragma unroll
        for (int it = 0; it < 8; it++) {
            int idx = tid + it * 256;          // 128 rows x 16 chunks
            int r2 = idx >> 4, c2 = idx & 15;
            int grow = rowBase + r2;
            if (grow < M) {
                uint4 v = *(const uint4*)&S[r2 * 136 + c2 * 8];
                *(uint4*)((ushort*)outv + (long)grow * ostride + colBase + c2 * 8) = v;
            }
        }
    } else {
        // fp32 epilogue: two half-tiles of 64 rows (stride 132 floats)
        float* Sf = (float*)S;
#pragma unroll
        for (int p = 0; p < 2; p++) {
            if (p) __syncthreads();
            if ((wr >> 6) == p) {
#pragma unroll
                for (int nn = 0; nn < 4; nn++) {
                    int cl = wc + nn * 16 + l15;
                    float bv = bias[colBase + cl];
#pragma unroll
                    for (int m = 0; m < 4; m++) {
                        int rl = m * 16 + lk * 4;
#pragma unroll
                        for (int j = 0; j < 4; j++)
                            Sf[(rl + j) * 132 + cl] = fast_tanh(acc[m][nn][j] + bv);
                    }
                }
            }
            __syncthreads();
#pragma unroll
            for (int it = 0; it < 8; it++) {
                int idx = tid + it * 256;       // 64 rows x 32 float4-chunks
                int r2 = idx >> 5, c2 = idx & 31;
                int grow = rowBase + p * 64 + r2;
                if (grow < M) {
                    float4 v = *(const float4*)&Sf[r2 * 132 + c2 * 4];
                    *(float4*)((float*)outv + (long)grow * ostride + colBase + c2 * 4) = v;
                }
            }
        }
    }
}

extern "C" void kernel_launch(void* const* d_in, const int* in_sizes, int n_in,
                              void* d_out, int out_size, void* d_ws, size_t ws_size,
                              hipStream_t stream) {
    const float* x       = (const float*)d_in[0];
    const int*   pos_src = (const int*)d_in[1];
    const int*   pos_dst = (const int*)d_in[2];
    const int*   neg_src = (const int*)d_in[3];
    const int*   neg_dst = (const int*)d_in[4];
    const float* W_oneB  = (const float*)d_in[5];
    const float* b_oneB  = (const float*)d_in[6];
    const float* W_oneH  = (const float*)d_in[7];
    const float* b_oneH  = (const float*)d_in[8];
    const float* W_twoB  = (const float*)d_in[9];
    const float* b_twoB  = (const float*)d_in[10];
    const float* W_twoH  = (const float*)d_in[11];
    const float* b_twoH  = (const float*)d_in[12];
    const float* W_four  = (const float*)d_in[13];
    const float* b_four  = (const float*)d_in[14];

    const int D = in_sizes[6];        // 128
    const int N = in_sizes[0] / D;    // 50000  (< 65536 -> ushort perm ok)
    const int E = in_sizes[1];        // 800000

    ushort* wb = (ushort*)d_ws;
    size_t ND = (size_t)N * D;
    ushort* xb   = wb;
    ushort* mpn  = wb + ND;
    ushort* hbn2 = wb;
    ushort* hbn1 = wb + 4 * ND;
    ushort* pos2 = wb + 6 * ND;
    ushort* neg2 = wb + 8 * ND;
    ushort* wt1  = wb + 10 * ND;
    ushort* wt2  = wt1 + 2 * D * D;
    ushort* wt3  = wt2 + 2 * D * D;
    ushort* wt4  = wt3 + 6 * D * D;
    ushort* wt5  = wt4 + 6 * D * D;
    ushort* p_perm = wt5 + 4 * D * D;
    ushort* n_perm = p_perm + E;
    ushort* p_rank = n_perm + E;
    ushort* n_rank = p_rank + E;
    int* ip    = (int*)(n_rank + E);
    int* p_row = ip;
    int* n_row = ip + (N + 1);

    int gridE  = (E + THREADS - 1) / THREADS;
    long n8    = (long)ND / 8;
    int cvtB   = (int)((n8 + THREADS - 1) / THREADS);
    int trB    = (20 * D * D + THREADS - 1) / THREADS;
    int gridN4 = (N + 3) / 4;
    int gx = (N + 127) / 128;

    // CSR build + conversions (fused)
    hipMemsetAsync(ip, 0, 2 * (size_t)(N + 1) * sizeof(int), stream);
    count_convert<<<gridE + cvtB, THREADS, 0, stream>>>(
        pos_dst, neg_dst, p_row, n_row, p_rank, n_rank, E, gridE, x, xb, n8);
    scan2_kernel<<<2, 1024, 0, stream>>>(p_row, n_row, N);
    fill_transpose<<<gridE + trB, THREADS, 0, stream>>>(
        pos_src, pos_dst, neg_src, neg_dst, p_row, n_row, p_rank, n_rank,
        p_perm, n_perm, E, gridE,
        W_oneB, wt1, W_oneH, wt2, W_twoB, wt3, W_twoH, wt4, W_four, wt5, D);

    // layer 1
    gather_l1<<<gridN4, THREADS, 0, stream>>>(p_row, n_row, p_perm, n_perm, xb, mpn, N);
    mfma_gemm_tanh<256, 128, 128, false, 2><<<gx * 2, THREADS, 0, stream>>>(
        mpn, mpn + 128, 256, xb, xb, 128,
        wt1, wt2, b_oneB, b_oneH, hbn1, hbn1 + 128, 256, N);

    // layer 2
    gather_l2<<<gridN4, THREADS, 0, stream>>>(p_row, n_row, p_perm, n_perm,
                                              hbn1, pos2, neg2, N);
    mfma_gemm_tanh<384, 256, 256, false, 4><<<gx * 4, THREADS, 0, stream>>>(
        pos2, neg2, 256, hbn1, hbn1 + 128, 256,
        wt3, wt4, b_twoB, b_twoH, hbn2, hbn2 + 256, 512, N);

    // final
    mfma_gemm_tanh<512, 128, 512, true, 1><<<gx, THREADS, 0, stream>>>(
        hbn2, hbn2, 512, hbn2, hbn2, 512,
        wt5, wt5, b_four, b_four, d_out, d_out, 128, N);
}